// Round 1
// 731.695 us; speedup vs baseline: 1.0685x; 1.0685x over previous
//
#include <hip/hip_runtime.h>

// B=32, C=64, H=W=128, RADIUS=30
// d_ws layout: [0, 134MB) = x_h, [134MB, 268MB) = e   (em never materialized)

__device__ __forceinline__ float2 cmul(float2 a, float2 b) {
  return make_float2(a.x * b.x - a.y * b.y, a.x * b.y + a.y * b.x);
}
__device__ __forceinline__ float2 cadd(float2 a, float2 b) {
  return make_float2(a.x + b.x, a.y + b.y);
}
__device__ __forceinline__ float2 csub(float2 a, float2 b) {
  return make_float2(a.x - b.x, a.y - b.y);
}
__device__ __forceinline__ float2 conjf2(float2 a) {
  return make_float2(a.x, -a.y);
}

// XOR-swizzled LDS layout: element (r,c) at (r<<7)|(c^(r&31)).
__device__ __forceinline__ int swz(int r, int c) {
  return (r << 7) | (c ^ (r & 31));
}

// ---------------------------------------------------------------------------
// Kernel 1: FFT high-pass, radix-8 passes (3 radix-2 stages fused in regs).
// (unchanged this round)
// ---------------------------------------------------------------------------
__device__ __forceinline__ void bf3_fwd(float2 x[8], float2 t0, float2 t1,
                                        float2 t2, float2 t3, float2 tp0,
                                        float2 tp1, float2 tpp) {
  float2 y0 = cadd(x[0], x[4]), y4 = cmul(csub(x[0], x[4]), t0);
  float2 y1 = cadd(x[1], x[5]), y5 = cmul(csub(x[1], x[5]), t1);
  float2 y2 = cadd(x[2], x[6]), y6 = cmul(csub(x[2], x[6]), t2);
  float2 y3 = cadd(x[3], x[7]), y7 = cmul(csub(x[3], x[7]), t3);
  float2 z0 = cadd(y0, y2), z2 = cmul(csub(y0, y2), tp0);
  float2 z1 = cadd(y1, y3), z3 = cmul(csub(y1, y3), tp1);
  float2 z4 = cadd(y4, y6), z6 = cmul(csub(y4, y6), tp0);
  float2 z5 = cadd(y5, y7), z7 = cmul(csub(y5, y7), tp1);
  x[0] = cadd(z0, z1); x[1] = cmul(csub(z0, z1), tpp);
  x[2] = cadd(z2, z3); x[3] = cmul(csub(z2, z3), tpp);
  x[4] = cadd(z4, z5); x[5] = cmul(csub(z4, z5), tpp);
  x[6] = cadd(z6, z7); x[7] = cmul(csub(z6, z7), tpp);
}

__device__ __forceinline__ void bf3_inv(float2 x[8], float2 w0, float2 w10,
                                        float2 w11, float2 w20, float2 w21,
                                        float2 w22, float2 w23) {
  float2 t;
  t = cmul(x[1], w0); float2 y0 = cadd(x[0], t), y1 = csub(x[0], t);
  t = cmul(x[3], w0); float2 y2 = cadd(x[2], t), y3 = csub(x[2], t);
  t = cmul(x[5], w0); float2 y4 = cadd(x[4], t), y5 = csub(x[4], t);
  t = cmul(x[7], w0); float2 y6 = cadd(x[6], t), y7 = csub(x[6], t);
  t = cmul(y2, w10); float2 z0 = cadd(y0, t), z2 = csub(y0, t);
  t = cmul(y3, w11); float2 z1 = cadd(y1, t), z3 = csub(y1, t);
  t = cmul(y6, w10); float2 z4 = cadd(y4, t), z6 = csub(y4, t);
  t = cmul(y7, w11); float2 z5 = cadd(y5, t), z7 = csub(y5, t);
  t = cmul(z4, w20); x[0] = cadd(z0, t); x[4] = csub(z0, t);
  t = cmul(z5, w21); x[1] = cadd(z1, t); x[5] = csub(z1, t);
  t = cmul(z6, w22); x[2] = cadd(z2, t); x[6] = csub(z2, t);
  t = cmul(z7, w23); x[3] = cadd(z3, t); x[7] = csub(z3, t);
}

template <bool COL, int S>
__device__ __forceinline__ void fwd_tri(float2* img, const float2* tw,
                                        int tid) {
  constexpr int m4 = 1 << (S - 2);
#pragma unroll
  for (int k = 0; k < 2; ++k) {
    int g = tid + (k << 10);
    int line = COL ? (g & 127) : (g >> 4);
    int gidx = COL ? (g >> 7) : (g & 15);
    int q = gidx >> (S - 2);
    int j = gidx & (m4 - 1);
    int off0 = (q << (S + 1)) + j;
    int ad[8];
    float2 x[8];
#pragma unroll
    for (int i = 0; i < 8; ++i) {
      int el = off0 + i * m4;
      ad[i] = COL ? swz(el, line) : swz(line, el);
      x[i] = img[ad[i]];
    }
    bf3_fwd(x, tw[j << (6 - S)], tw[(j + m4) << (6 - S)],
            tw[(j + 2 * m4) << (6 - S)], tw[(j + 3 * m4) << (6 - S)],
            tw[j << (7 - S)], tw[(j + m4) << (7 - S)], tw[j << (8 - S)]);
#pragma unroll
    for (int i = 0; i < 8; ++i) img[ad[i]] = x[i];
  }
  __syncthreads();
}

__device__ __forceinline__ void fwd_rows6_g(const float* __restrict__ p0,
                                            const float* __restrict__ p1,
                                            float2* img, const float2* tw,
                                            int tid) {
#pragma unroll
  for (int k = 0; k < 2; ++k) {
    int g = tid + (k << 10);
    int line = g >> 4;
    int j = g & 15;
    float2 x[8];
#pragma unroll
    for (int i = 0; i < 8; ++i) {
      int a = (line << 7) + j + (i << 4);
      x[i] = make_float2(p0[a], p1[a]);
    }
    bf3_fwd(x, tw[j], tw[j + 16], tw[j + 32], tw[j + 48], tw[j << 1],
            tw[(j + 16) << 1], tw[j << 2]);
#pragma unroll
    for (int i = 0; i < 8; ++i) img[swz(line, j + (i << 4))] = x[i];
  }
  __syncthreads();
}

__device__ __forceinline__ void fwd_last_rows(float2* img, int tid) {
#pragma unroll
  for (int k = 0; k < 8; ++k) {
    int g = tid + (k << 10);
    int line = g >> 6;
    int pr = g & 63;
    int e0 = pr << 1;
    int a0 = swz(line, e0), a1 = swz(line, e0 + 1);
    float2 a = img[a0], b = img[a1];
    img[a0] = cadd(a, b);
    img[a1] = csub(a, b);
  }
  __syncthreads();
}

__device__ __forceinline__ void fwd_last_cols_mask(float2* img, int tid) {
#pragma unroll
  for (int k = 0; k < 8; ++k) {
    int g = tid + (k << 10);
    int line = g & 127;
    int pr = g >> 7;
    int e0 = pr << 1;
    int a0 = swz(e0, line), a1 = swz(e0 + 1, line);
    float2 a = img[a0], b = img[a1];
    float2 s = cadd(a, b), d = csub(a, b);
    int v = __brev((unsigned)line) >> 25;
    int dv = v - ((v >= 64) << 7);
    int u0 = __brev((unsigned)e0) >> 25;
    int du0 = u0 - ((u0 >= 64) << 7);
    int u1 = __brev((unsigned)(e0 + 1)) >> 25;
    int du1 = u1 - ((u1 >= 64) << 7);
    int dvv = dv * dv;
    img[a0] = (du0 * du0 + dvv < 900) ? make_float2(0.f, 0.f) : s;
    img[a1] = (du1 * du1 + dvv < 900) ? make_float2(0.f, 0.f) : d;
  }
  __syncthreads();
}

template <bool COL, int S>
__device__ __forceinline__ void inv_tri(float2* img, const float2* tw,
                                        int tid) {
  constexpr int m = 1 << S;
#pragma unroll
  for (int k = 0; k < 2; ++k) {
    int g = tid + (k << 10);
    int line = COL ? (g & 127) : (g >> 4);
    int gidx = COL ? (g >> 7) : (g & 15);
    int q = gidx >> S;
    int j = gidx & (m - 1);
    int off0 = (q << (S + 3)) + j;
    int ad[8];
    float2 x[8];
#pragma unroll
    for (int i = 0; i < 8; ++i) {
      int el = off0 + i * m;
      ad[i] = COL ? swz(el, line) : swz(line, el);
      x[i] = img[ad[i]];
    }
    bf3_inv(x, conjf2(tw[j << (6 - S)]), conjf2(tw[j << (5 - S)]),
            conjf2(tw[(j + m) << (5 - S)]), conjf2(tw[j << (4 - S)]),
            conjf2(tw[(j + m) << (4 - S)]), conjf2(tw[(j + 2 * m) << (4 - S)]),
            conjf2(tw[(j + 3 * m) << (4 - S)]));
#pragma unroll
    for (int i = 0; i < 8; ++i) img[ad[i]] = x[i];
  }
  __syncthreads();
}

__device__ __forceinline__ void inv_last_cols(float2* img, const float2* tw,
                                              int tid) {
#pragma unroll
  for (int k = 0; k < 8; ++k) {
    int g = tid + (k << 10);
    int line = g & 127;
    int j = g >> 7;
    int a0 = swz(j, line), a1 = swz(j + 64, line);
    float2 a = img[a0], b = img[a1];
    float2 t = cmul(b, conjf2(tw[j]));
    img[a0] = cadd(a, t);
    img[a1] = csub(a, t);
  }
  __syncthreads();
}

__device__ __forceinline__ void inv_last_rows_store(const float2* img,
                                                    const float2* tw,
                                                    float* __restrict__ q0,
                                                    float* __restrict__ q1,
                                                    int tid) {
#pragma unroll
  for (int k = 0; k < 8; ++k) {
    int g = tid + (k << 10);
    int line = g >> 6;
    int j = g & 63;
    float2 a = img[swz(line, j)], b = img[swz(line, j + 64)];
    float2 t = cmul(b, conjf2(tw[j]));
    float2 o0 = cadd(a, t), o1 = csub(a, t);
    int p = (line << 7) + j;
    q0[p] = fabsf(o0.x) * 6.103515625e-05f;
    q1[p] = fabsf(o0.y) * 6.103515625e-05f;
    q0[p + 64] = fabsf(o1.x) * 6.103515625e-05f;
    q1[p + 64] = fabsf(o1.y) * 6.103515625e-05f;
  }
}

__global__ __launch_bounds__(1024) void k_fft_hp(const float* __restrict__ x,
                                                 float* __restrict__ xh) {
  __shared__ float2 img[16384];
  __shared__ float2 tw[64];
  const int tid = threadIdx.x;
  const size_t base = (size_t)blockIdx.x * 32768;
  const float* p0 = x + base;
  const float* p1 = p0 + 16384;

  if (tid < 64) {
    float ang = -0.04908738521234052f * (float)tid;
    tw[tid] = make_float2(cosf(ang), sinf(ang));
  }
  __syncthreads();

  fwd_rows6_g(p0, p1, img, tw, tid);
  fwd_tri<false, 3>(img, tw, tid);
  fwd_last_rows(img, tid);
  fwd_tri<true, 6>(img, tw, tid);
  fwd_tri<true, 3>(img, tw, tid);
  fwd_last_cols_mask(img, tid);

  inv_tri<true, 0>(img, tw, tid);
  inv_tri<true, 3>(img, tw, tid);
  inv_last_cols(img, tw, tid);
  inv_tri<false, 0>(img, tw, tid);
  inv_tri<false, 3>(img, tw, tid);
  inv_last_rows_store(img, tw, xh + base, xh + base + 16384, tid);
}

// ---------------------------------------------------------------------------
// Kernel 2: fused DWSConv — REWRITTEN.
// One pixel per thread, acc[64] in registers; dwb LDS round-trip eliminated.
// Pointwise weights fetched as wave-uniform rows -> compiler scalarizes to
// s_load (verified on prev version: SGPR=112 with VGPR=88 proves uniform
// weight loads already went to SMEM). Tile 32x8: wave lanes span x=0..31 at
// LDS stride 1 and two rows 34 floats apart -> exactly 2 lanes/bank = free.
// LDS 21.8 KB (was 39.9), 2 barriers/chunk * 4 chunks (was 3 * 4).
// ---------------------------------------------------------------------------
__global__ __launch_bounds__(256, 4) void k_dws(
    const float* __restrict__ xh, float* __restrict__ e,
    const float* __restrict__ dw_w, const float* __restrict__ s1,
    const float* __restrict__ b1, const float* __restrict__ pw_w,
    const float* __restrict__ s2, const float* __restrict__ b2) {
  // halo tile for 16 channels: 10 rows x 34 cols each (pad=1 on all sides)
  __shared__ float inT[16][340];

  const int t = threadIdx.x;
  const int bb = blockIdx.x >> 6;          // batch
  const int ty = (blockIdx.x >> 2) & 15;   // 16 row-tiles of 8
  const int tx = blockIdx.x & 3;           // 4 col-tiles of 32
  const int r = t >> 5;                    // 0..7  (px row in tile)
  const int x = t & 31;                    // 0..31 (px col in tile)

  const int gy0 = (ty << 3) - 1;
  const int gx0 = (tx << 5) - 1;

  float acc[64];
#pragma unroll
  for (int o = 0; o < 64; ++o) acc[o] = 0.f;

#pragma unroll 1
  for (int chunk = 0; chunk < 4; ++chunk) {
    __syncthreads();  // protect inT from previous chunk's readers
    // stage 16 channels' 10x34 halo tiles (5440 floats, ~21/thread)
    for (int i = t; i < 5440; i += 256) {
      int c = i / 340;
      int rem = i - c * 340;
      int iy = rem / 34;
      int ix = rem - iy * 34;
      int gy = gy0 + iy;
      int gx = gx0 + ix;
      float v = 0.f;
      if (gy >= 0 && gy < 128 && gx >= 0 && gx < 128)
        v = xh[(((size_t)bb * 64 + (chunk << 4) + c) << 14) + (gy << 7) + gx];
      inT[c][rem] = v;
    }
    __syncthreads();

    // depthwise 3x3 + BN + ReLU for this thread's pixel, 16 channels -> regs
    float dwv[16];
#pragma unroll
    for (int c = 0; c < 16; ++c) {
      const int cg = (chunk << 4) + c;
      const float* wp = dw_w + cg * 9;     // uniform -> s_load
      const float* p = &inT[c][r * 34 + x];
      float s = wp[0] * p[0];
      s = fmaf(wp[1], p[1], s);
      s = fmaf(wp[2], p[2], s);
      s = fmaf(wp[3], p[34], s);
      s = fmaf(wp[4], p[35], s);
      s = fmaf(wp[5], p[36], s);
      s = fmaf(wp[6], p[68], s);
      s = fmaf(wp[7], p[69], s);
      s = fmaf(wp[8], p[70], s);
      dwv[c] = fmaxf(fmaf(s, s1[cg], b1[cg]), 0.f);
    }

    // pointwise: acc[o] += sum_c pw_w[o][cg]*dwv[c]; weight rows are
    // wave-uniform 16-float contiguous blocks -> SMEM loads, zero LDS.
#pragma unroll
    for (int o = 0; o < 64; ++o) {
      const float* w = pw_w + (o << 6) + (chunk << 4);
#pragma unroll
      for (int c = 0; c < 16; ++c) acc[o] = fmaf(w[c], dwv[c], acc[o]);
    }
  }

  // epilogue: BN + ReLU, store. Wave covers 2 rows x 32 cols = two full
  // 128B lines per store instruction.
  const int gy = (ty << 3) + r;
  const int gx = (tx << 5) + x;
#pragma unroll
  for (int o = 0; o < 64; ++o) {
    float ev = fmaxf(fmaf(acc[o], s2[o], b2[o]), 0.f);
    e[(((size_t)bb * 64 + o) << 14) + (gy << 7) + gx] = ev;
  }
}

// ---------------------------------------------------------------------------
// Kernel 3: branches + edge + final via g-vector collapse (unchanged).
// ---------------------------------------------------------------------------
struct BrParams {
  const float *dw1w, *dw1s, *dw1b, *pw1w, *pw1s, *pw1b;
  const float *dw2w, *dw2s, *dw2b, *pw2w, *pw2s, *pw2b;
  const float *dw3w, *dw3s, *dw3b, *pw3w, *pw3s, *pw3b;
  const float *dw4w, *dw4s, *dw4b, *pw4w, *pw4s, *pw4b;
};

__global__ __launch_bounds__(256) void k_edge_final(
    const float* __restrict__ e, const float* __restrict__ x,
    float* __restrict__ out, BrParams P, const float* __restrict__ cw,
    const float* __restrict__ cs, const float* __restrict__ cb) {
  __shared__ float sE[4][1118];
  __shared__ float dwW2[576], dwW3[576], dwW4[576];
  __shared__ float dw1Ws[64];
  __shared__ float dwSs[4][64], dwBs[4][64];
  __shared__ float gs[4][64];
  __shared__ float cws[64];
  __shared__ float pss[4][16], pbs[4][16];
  __shared__ float KbS, swS;

  const int t = threadIdx.x;
  const int bb = blockIdx.x >> 5;
  const int ty = (blockIdx.x >> 2) & 7;
  const int tx = blockIdx.x & 3;
  const int r = t >> 4;
  const int x0 = (t & 15) << 1;

  for (int i = t; i < 576; i += 256) {
    dwW2[i] = P.dw2w[i];
    dwW3[i] = P.dw3w[i];
    dwW4[i] = P.dw4w[i];
  }
  if (t < 64) {
    dw1Ws[t] = P.dw1w[t];
    cws[t] = cw[t];
    dwSs[0][t] = P.dw1s[t]; dwBs[0][t] = P.dw1b[t];
    dwSs[1][t] = P.dw2s[t]; dwBs[1][t] = P.dw2b[t];
    dwSs[2][t] = P.dw3s[t]; dwBs[2][t] = P.dw3b[t];
    dwSs[3][t] = P.dw4s[t]; dwBs[3][t] = P.dw4b[t];
  }
  if (t < 16) {
    pss[0][t] = P.pw1s[t]; pbs[0][t] = P.pw1b[t];
    pss[1][t] = P.pw2s[t]; pbs[1][t] = P.pw2b[t];
    pss[2][t] = P.pw3s[t]; pbs[2][t] = P.pw3b[t];
    pss[3][t] = P.pw4s[t]; pbs[3][t] = P.pw4b[t];
  }
  __syncthreads();
  {
    const int q = t >> 6, c = t & 63;
    const float* pwW = (q == 0) ? P.pw1w : (q == 1) ? P.pw2w
                        : (q == 2) ? P.pw3w : P.pw4w;
    float gv = 0.f;
#pragma unroll
    for (int o = 0; o < 16; ++o)
      gv = fmaf(cws[(q << 4) + o] * pss[q][o], pwW[(o << 6) + c], gv);
    gs[q][c] = gv;
  }
  if (t == 0) {
    float kb = 0.f, sw = 0.f;
#pragma unroll
    for (int i = 0; i < 64; ++i) {
      kb = fmaf(cws[i], pbs[i >> 4][i & 15], kb);
      sw += cws[i];
    }
    KbS = kb;
    swS = sw;
  }

  float edge_acc[2] = {0.f, 0.f};
  float es[2] = {0.f, 0.f};
  float sx[2] = {0.f, 0.f};
  const int gy = (ty << 4) + r;
  const int gx0 = (tx << 5) + x0;

#pragma unroll 1
  for (int ch = 0; ch < 16; ++ch) {
    __syncthreads();
    for (int i = t; i < 4368; i += 256) {
      int j = i / 1092;
      int rem = i - j * 1092;
      int iy = rem / 42;
      int ix = rem - iy * 42;
      int gyy = (ty << 4) + iy - 5;
      int gxx = (tx << 5) + ix - 5;
      float v = 0.f;
      if (gyy >= 0 && gyy < 128 && gxx >= 0 && gxx < 128)
        v = e[(((size_t)bb * 64 + (ch << 2) + j) << 14) + (gyy << 7) + gxx];
      sE[j][iy * 43 + ix] = v;
    }
    __syncthreads();
#pragma unroll 1
    for (int j = 0; j < 4; ++j) {
      const int c = (ch << 2) + j;
      const float* Pc = &sE[j][(r + 5) * 43 + x0 + 5];
      float cr[12], m1[4], p1[4], m3[8], p3[8], m5[12], p5[12];
#pragma unroll
      for (int i = 0; i < 12; ++i) cr[i] = Pc[i - 5];
#pragma unroll
      for (int i = 0; i < 4; ++i) m1[i] = Pc[-43 + i - 1];
#pragma unroll
      for (int i = 0; i < 4; ++i) p1[i] = Pc[43 + i - 1];
#pragma unroll
      for (int i = 0; i < 8; ++i) m3[i] = Pc[-129 + i - 3];
#pragma unroll
      for (int i = 0; i < 8; ++i) p3[i] = Pc[129 + i - 3];
#pragma unroll
      for (int i = 0; i < 12; ++i) m5[i] = Pc[-215 + i - 5];
#pragma unroll
      for (int i = 0; i < 12; ++i) p5[i] = Pc[215 + i - 5];

      const float cwv = cws[c];
      const float g0 = gs[0][c], g1 = gs[1][c], g2 = gs[2][c], g3 = gs[3][c];
      const float w1c = dw1Ws[c];
      const float* w2 = &dwW2[c * 9];
      const float* w3 = &dwW3[c * 9];
      const float* w4 = &dwW4[c * 9];
      const float sA = dwSs[0][c], bA = dwBs[0][c];
      const float sB = dwSs[1][c], bB = dwBs[1][c];
      const float sC = dwSs[2][c], bC = dwBs[2][c];
      const float sD = dwSs[3][c], bD = dwBs[3][c];
#pragma unroll
      for (int k = 0; k < 2; ++k) {
        const float ec = cr[k + 5];
        es[k] = fmaf(cwv, ec, es[k]);
        float d0 = fmaxf(fmaf(ec * w1c, sA, bA), 0.f);
        float s1v = w2[0] * m1[k];
        s1v = fmaf(w2[1], m1[k + 1], s1v);
        s1v = fmaf(w2[2], m1[k + 2], s1v);
        s1v = fmaf(w2[3], cr[k + 4], s1v);
        s1v = fmaf(w2[4], cr[k + 5], s1v);
        s1v = fmaf(w2[5], cr[k + 6], s1v);
        s1v = fmaf(w2[6], p1[k], s1v);
        s1v = fmaf(w2[7], p1[k + 1], s1v);
        s1v = fmaf(w2[8], p1[k + 2], s1v);
        float d1 = fmaxf(fmaf(s1v, sB, bB), 0.f);
        float s2v = w3[0] * m3[k];
        s2v = fmaf(w3[1], m3[k + 3], s2v);
        s2v = fmaf(w3[2], m3[k + 6], s2v);
        s2v = fmaf(w3[3], cr[k + 2], s2v);
        s2v = fmaf(w3[4], cr[k + 5], s2v);
        s2v = fmaf(w3[5], cr[k + 8], s2v);
        s2v = fmaf(w3[6], p3[k], s2v);
        s2v = fmaf(w3[7], p3[k + 3], s2v);
        s2v = fmaf(w3[8], p3[k + 6], s2v);
        float d2 = fmaxf(fmaf(s2v, sC, bC), 0.f);
        float s3v = w4[0] * m5[k];
        s3v = fmaf(w4[1], m5[k + 5], s3v);
        s3v = fmaf(w4[2], m5[k + 10], s3v);
        s3v = fmaf(w4[3], cr[k], s3v);
        s3v = fmaf(w4[4], cr[k + 5], s3v);
        s3v = fmaf(w4[5], cr[k + 10], s3v);
        s3v = fmaf(w4[6], p5[k], s3v);
        s3v = fmaf(w4[7], p5[k + 5], s3v);
        s3v = fmaf(w4[8], p5[k + 10], s3v);
        float d3 = fmaxf(fmaf(s3v, sD, bD), 0.f);
        float ea = fmaf(g0, d0, edge_acc[k]);
        ea = fmaf(g1, d1, ea);
        ea = fmaf(g2, d2, ea);
        edge_acc[k] = fmaf(g3, d3, ea);
      }
      const float2 xv = *(const float2*)(x + (((size_t)bb * 64 + c) << 14) +
                                         (gy << 7) + gx0);
      sx[0] = fmaf(cwv, xv.x, sx[0]);
      sx[1] = fmaf(cwv, xv.y, sx[1]);
    }
  }

  const float csv = cs[0], cbv = cb[0];
  const float kb = KbS, sw = swS;
  float2 o2;
  float e0 = fmaxf(fmaf(edge_acc[0] + kb + es[0], csv, cbv), 0.f);
  float e1 = fmaxf(fmaf(edge_acc[1] + kb + es[1], csv, cbv), 0.f);
  o2.x = fmaf(sx[0] + e0 * sw, csv, cbv);
  o2.y = fmaf(sx[1] + e1 * sw, csv, cbv);
  *(float2*)(out + ((size_t)bb << 14) + (gy << 7) + gx0) = o2;
}

// ---------------------------------------------------------------------------
extern "C" void kernel_launch(void* const* d_in, const int* in_sizes, int n_in,
                              void* d_out, int out_size, void* d_ws,
                              size_t ws_size, hipStream_t stream) {
  (void)in_sizes; (void)n_in; (void)out_size; (void)ws_size;
  const float* x = (const float*)d_in[0];
  const float* dws_dw = (const float*)d_in[1];
  const float* dws_s1 = (const float*)d_in[2];
  const float* dws_b1 = (const float*)d_in[3];
  const float* dws_pw = (const float*)d_in[4];
  const float* dws_s2 = (const float*)d_in[5];
  const float* dws_b2 = (const float*)d_in[6];
  BrParams P;
  P.dw1w = (const float*)d_in[7];  P.dw1s = (const float*)d_in[8];
  P.dw1b = (const float*)d_in[9];  P.pw1w = (const float*)d_in[10];
  P.pw1s = (const float*)d_in[11]; P.pw1b = (const float*)d_in[12];
  P.dw2w = (const float*)d_in[13]; P.dw2s = (const float*)d_in[14];
  P.dw2b = (const float*)d_in[15]; P.pw2w = (const float*)d_in[16];
  P.pw2s = (const float*)d_in[17]; P.pw2b = (const float*)d_in[18];
  P.dw3w = (const float*)d_in[19]; P.dw3s = (const float*)d_in[20];
  P.dw3b = (const float*)d_in[21]; P.pw3w = (const float*)d_in[22];
  P.pw3s = (const float*)d_in[23]; P.pw3b = (const float*)d_in[24];
  P.dw4w = (const float*)d_in[25]; P.dw4s = (const float*)d_in[26];
  P.dw4b = (const float*)d_in[27]; P.pw4w = (const float*)d_in[28];
  P.pw4s = (const float*)d_in[29]; P.pw4b = (const float*)d_in[30];
  const float* conv_w = (const float*)d_in[31];
  const float* conv_s = (const float*)d_in[32];
  const float* conv_b = (const float*)d_in[33];

  float* xh = (float*)d_ws;                 // 134 MB
  float* e = xh + (size_t)33554432;         // 134 MB

  hipLaunchKernelGGL(k_fft_hp, dim3(1024), dim3(1024), 0, stream, x, xh);
  hipLaunchKernelGGL(k_dws, dim3(2048), dim3(256), 0, stream, xh, e, dws_dw,
                     dws_s1, dws_b1, dws_pw, dws_s2, dws_b2);
  hipLaunchKernelGGL(k_edge_final, dim3(1024), dim3(256), 0, stream, e, x,
                     (float*)d_out, P, conv_w, conv_s, conv_b);
}